// Round 6
// baseline (31.273 us; speedup 1.0000x reference)
//
#include <hip/hip_runtime.h>

// Problem constants (fixed by setup_inputs shapes)
#define HOUT 39
#define WOUT 39
#define COUT 64
#define HIN  160
#define WIN  160
#define CIN  4
#define F    8
#define S    4
#define G    3    // positions per block: 1521 = 3 * 507 exactly

// Block = 3 consecutive output positions (ij, ij+1, ij+2); 4 waves split the
// 256-element patch (k = (px*8+py)*4+pc) into 64-wide segments; lane = c.
//
// w-reuse: each w[k][c] is loaded ONCE per wave (coalesced over lane=c) and
// feeds all 3 positions -> w L2 traffic drops 3x (97 MB -> 32 MB), which was
// the kernel-exec floor. x for each position sits in one register across the
// wave's 64 lanes (lane q holds x for k=kb+q), broadcast via v_readlane with
// literal lane indices (SALU-side, folds into v_mul as SGPR operand).
// Argmax: 4 independent 16-long chains per position (12 chains of ILP),
// merged ascending-k with strict > (first-occurrence ties = jnp.argmax),
// cross-wave merge via LDS, 192 threads scatter with atomicAdd into the
// memset-zeroed output.
__global__ __launch_bounds__(256) void argmax_rel_kernel(
    const float* __restrict__ rel,   // [39,39,64]
    const float* __restrict__ x,     // [160,160,4]
    const float* __restrict__ w,     // [8,8,4,64] flat: [k][c]
    float* __restrict__ out)         // [160,160,4], pre-zeroed
{
    const int ijb = blockIdx.x * G;             // first position of this block
    const int wv  = threadIdx.x >> 6;           // wave -> k in [wv*64, wv*64+64)
    const int c   = threadIdx.x & 63;

    // hoisted: relevance for the scatter phase (thread tid -> (g=tid>>6, c))
    float r = 0.0f;
    if (threadIdx.x < G * COUT) r = rel[ijb * COUT + threadIdx.x];

    const int kb = wv * 64;                     // patch rows px = 2wv, 2wv+1

    // per-position x window: lane q holds x for k = kb+q
    int xb[G];
    #pragma unroll
    for (int g = 0; g < G; ++g) {
        const int ij = ijb + g;
        const int i  = ij / WOUT;
        const int j  = ij - i * WOUT;
        const float* rowb = x + ((S * i + 2 * wv) * WIN + S * j) * CIN;
        const float xv = (c < 32) ? rowb[c] : rowb[WIN * CIN + (c - 32)];
        xb[g] = __float_as_int(xv);
    }

    const float* wp = w + kb * COUT + c;        // coalesced over lanes

    float m[G][4];
    int   a[G][4];
    #pragma unroll
    for (int g = 0; g < G; ++g) {
        #pragma unroll
        for (int q = 0; q < 4; ++q) { m[g][q] = -__builtin_inff(); a[g][q] = kb + 16 * q; }
    }

    #pragma unroll
    for (int t = 0; t < 16; ++t) {
        const float w0 = wp[(t)      * COUT];   // one w read feeds 3 positions
        const float w1 = wp[(t + 16) * COUT];
        const float w2 = wp[(t + 32) * COUT];
        const float w3 = wp[(t + 48) * COUT];
        #pragma unroll
        for (int g = 0; g < G; ++g) {
            const float x0 = __int_as_float(__builtin_amdgcn_readlane(xb[g], t));
            const float x1 = __int_as_float(__builtin_amdgcn_readlane(xb[g], t + 16));
            const float x2 = __int_as_float(__builtin_amdgcn_readlane(xb[g], t + 32));
            const float x3 = __int_as_float(__builtin_amdgcn_readlane(xb[g], t + 48));
            const float p0 = x0 * w0;
            const float p1 = x1 * w1;
            const float p2 = x2 * w2;
            const float p3 = x3 * w3;
            if (p0 > m[g][0]) { m[g][0] = p0; a[g][0] = kb + t; }
            if (p1 > m[g][1]) { m[g][1] = p1; a[g][1] = kb + 16 + t; }
            if (p2 > m[g][2]) { m[g][2] = p2; a[g][2] = kb + 32 + t; }
            if (p3 > m[g][3]) { m[g][3] = p3; a[g][3] = kb + 48 + t; }
        }
    }

    __shared__ float lm[4][G][COUT];
    __shared__ int   la[4][G][COUT];
    #pragma unroll
    for (int g = 0; g < G; ++g) {
        // merge 4 chains, ascending k, strict > keeps earliest k on ties
        float mm = m[g][0]; int aa = a[g][0];
        if (m[g][1] > mm) { mm = m[g][1]; aa = a[g][1]; }
        if (m[g][2] > mm) { mm = m[g][2]; aa = a[g][2]; }
        if (m[g][3] > mm) { mm = m[g][3]; aa = a[g][3]; }
        lm[wv][g][c] = mm;
        la[wv][g][c] = aa;
    }
    __syncthreads();

    // final merge + scatter: thread tid -> position g = tid>>6, channel c
    if (threadIdx.x < G * COUT) {
        const int g = threadIdx.x >> 6;
        float bm = lm[0][g][c]; int ba = la[0][g][c];
        #pragma unroll
        for (int s = 1; s < 4; ++s) {            // ascending k segments
            const float sm = lm[s][g][c];
            if (sm > bm) { bm = sm; ba = la[s][g][c]; }
        }
        const int ij  = ijb + g;
        const int i   = ij / WOUT;
        const int j   = ij - i * WOUT;
        // ba = (px*8+py)*4+pc ; flat output index
        const int px_  = ba >> 5;               // patch row
        const int rem  = ba & 31;               // py*4+pc
        const int gx   = S * i + px_;
        const int flat = gx * (WIN * CIN) + (S * j) * CIN + rem;

        atomicAdd(out + flat, r);
    }
}

extern "C" void kernel_launch(void* const* d_in, const int* in_sizes, int n_in,
                              void* d_out, int out_size, void* d_ws, size_t ws_size,
                              hipStream_t stream) {
    const float* rel = (const float*)d_in[0];   // [1,39,39,64]
    const float* x   = (const float*)d_in[1];   // [1,160,160,4]
    const float* w   = (const float*)d_in[2];   // [8,8,4,64]
    float* out = (float*)d_out;                 // [1,160,160,4]

    // Output is scatter-add target: must start at zero every call.
    hipMemsetAsync(out, 0, (size_t)out_size * sizeof(float), stream);

    argmax_rel_kernel<<<(HOUT * WOUT) / G, 256, 0, stream>>>(rel, x, w, out);
}

// Round 8
// 17.684 us; speedup vs baseline: 1.7685x; 1.7685x over previous
//
#include <hip/hip_runtime.h>

// Problem constants (fixed by setup_inputs shapes)
#define HOUT 39
#define WOUT 39
#define COUT 64
#define HIN  160
#define WIN  160
#define CIN  4
#define F    8
#define S    4

// Block = one output position (i,j); 4 waves split the 256-element patch
// (k = (px*8+py)*4+pc) into 64-wide segments.
//
// Lane repack for vector loads: lane l = (h = l>>4 -> k-class mod 4,
// channels 4*(l&15)..+3). Per t-step one global_load_dwordx4 covers 4 k-rows
// of w (lane l reads k = kb+4t+h, channels 4(l&15)..+3):
//   float4 element = 16*(kb+4t+h) + (l&15) = [base + l] + t*64   (l = 16h+(l&15))
// Lane l's x value is a scalar load at per-lane base + compile-time offset
// (4 distinct addrs/wave -> L1 broadcast). No readlane/shfl in the hot loop.
//
// Argmax semantics (jnp.argmax = first occurrence = smallest k on ties):
//  - within a lane chain, k ascends -> strict > keeps earliest k;
//  - cross-h butterfly merge interleaves k-classes -> tie-aware predicate
//    (om > m) || (om == m && oa < a);
//  - cross-wave LDS merge walks segments in ascending k -> strict >.
__global__ __launch_bounds__(256) void argmax_rel_kernel(
    const float* __restrict__ rel,   // [39,39,64]
    const float* __restrict__ x,     // [160,160,4]
    const float* __restrict__ w,     // [8,8,4,64] flat: [k][c]
    float* __restrict__ out)         // [160,160,4], pre-zeroed
{
    const int ij = blockIdx.x;                  // 0..1520
    const int i  = ij / WOUT;
    const int j  = ij - i * WOUT;
    const int wv = threadIdx.x >> 6;            // wave -> k in [wv*64, wv*64+64)
    const int l  = threadIdx.x & 63;
    const int h  = l >> 4;                      // k-class (k === h mod 4)
    const int cg = (l & 15) << 2;               // channel group: cg..cg+3

    // hoisted: relevance for the final scatter (wave 0, lane c = l)
    const float r = rel[ij * COUT + l];

    const int kb = wv * 64;                     // patch rows px = 2wv, 2wv+1

    // w: lane l reads float4 element 16*(kb+4t+h) + (l&15) = base + l + t*64
    const float4* wp4 = (const float4*)(w + kb * COUT) + l;
    // x: per-lane base = row (2wv) of the patch, + h; offsets fold to imm
    const float* xb = x + ((S * i + 2 * wv) * WIN + S * j) * CIN + h;

    float m0 = -__builtin_inff(), m1 = m0, m2 = m0, m3 = m0;
    int   a0 = kb + h, a1 = a0, a2 = a0, a3 = a0;

    #pragma unroll
    for (int t = 0; t < 16; ++t) {
        const float4 w4 = wp4[t * 64];                           // k = kb+4t+h, 4 chans
        const float  xv = (t < 8) ? xb[4 * t]                    // row0: q = 4t+h
                                  : xb[WIN * CIN - 32 + 4 * t];  // row1: q-32
        const int    k  = kb + 4 * t + h;
        float p;
        p = xv * w4.x; if (p > m0) { m0 = p; a0 = k; }
        p = xv * w4.y; if (p > m1) { m1 = p; a1 = k; }
        p = xv * w4.z; if (p > m2) { m2 = p; a2 = k; }
        p = xv * w4.w; if (p > m3) { m3 = p; a3 = k; }
    }

    // butterfly merge across k-classes (lanes differing in bits 4,5);
    // classes interleave k mod 4 -> tie goes to smaller k
    #pragma unroll
    for (int mask = 16; mask <= 32; mask <<= 1) {
        const float om0 = __shfl_xor(m0, mask); const int oa0 = __shfl_xor(a0, mask);
        const float om1 = __shfl_xor(m1, mask); const int oa1 = __shfl_xor(a1, mask);
        const float om2 = __shfl_xor(m2, mask); const int oa2 = __shfl_xor(a2, mask);
        const float om3 = __shfl_xor(m3, mask); const int oa3 = __shfl_xor(a3, mask);
        if (om0 > m0 || (om0 == m0 && oa0 < a0)) { m0 = om0; a0 = oa0; }
        if (om1 > m1 || (om1 == m1 && oa1 < a1)) { m1 = om1; a1 = oa1; }
        if (om2 > m2 || (om2 == m2 && oa2 < a2)) { m2 = om2; a2 = oa2; }
        if (om3 > m3 || (om3 == m3 && oa3 < a3)) { m3 = om3; a3 = oa3; }
    }

    __shared__ float lm[4][COUT];
    __shared__ int   la[4][COUT];
    if (l < 16) {                                // h==0 lanes hold the result
        lm[wv][cg + 0] = m0; la[wv][cg + 0] = a0;
        lm[wv][cg + 1] = m1; la[wv][cg + 1] = a1;
        lm[wv][cg + 2] = m2; la[wv][cg + 2] = a2;
        lm[wv][cg + 3] = m3; la[wv][cg + 3] = a3;
    }
    __syncthreads();

    if (wv == 0) {                               // lane l = channel c
        float bm = lm[0][l]; int ba = la[0][l];
        #pragma unroll
        for (int s = 1; s < 4; ++s) {            // ascending k segments
            const float sm = lm[s][l];
            if (sm > bm) { bm = sm; ba = la[s][l]; }
        }
        // ba = (px*8+py)*4+pc ; flat output index
        const int px_  = ba >> 5;                // patch row
        const int rem  = ba & 31;                // py*4+pc
        const int gx   = S * i + px_;
        const int flat = gx * (WIN * CIN) + (S * j) * CIN + rem;

        atomicAdd(out + flat, r);
    }
}

extern "C" void kernel_launch(void* const* d_in, const int* in_sizes, int n_in,
                              void* d_out, int out_size, void* d_ws, size_t ws_size,
                              hipStream_t stream) {
    const float* rel = (const float*)d_in[0];   // [1,39,39,64]
    const float* x   = (const float*)d_in[1];   // [1,160,160,4]
    const float* w   = (const float*)d_in[2];   // [8,8,4,64]
    float* out = (float*)d_out;                 // [1,160,160,4]

    // Output is scatter-add target: must start at zero every call.
    hipMemsetAsync(out, 0, (size_t)out_size * sizeof(float), stream);

    argmax_rel_kernel<<<HOUT * WOUT, 256, 0, stream>>>(rel, x, w, out);
}

// Round 9
// 16.821 us; speedup vs baseline: 1.8591x; 1.0513x over previous
//
#include <hip/hip_runtime.h>

// Problem constants (fixed by setup_inputs shapes)
#define HOUT 39
#define WOUT 39
#define COUT 64
#define HIN  160
#define WIN  160
#define CIN  4
#define F    8
#define S    4

// Block = one output position (i,j); 4 waves split the 256-element patch
// (k = (px*8+py)*4+pc) into 4 contiguous segments of 64; lane = channel c.
// [R5 structure — measured best at 16.72 us. R8's dwordx4+butterfly variant
//  (33 VMEM + 24 shfl) measured 17.68: L1-hit VMEM issue is cheap; cross-lane
//  merge chains are not. R6's G=3 w-reuse measured 31.3: readlane streams
//  don't scale. Do not re-try those.]
//
// VMEM-slim scan: the 64 x-values of a wave's k-window are loaded ONCE,
// coalesced, into lane k's register; the unrolled loop broadcasts them via
// v_readlane (literal lane index -> SALU, SGPR operand folds into v_mul).
// Per wave: 65 VMEM loads. w reads coalesced over lane=c.
// Argmax: 4 independent 16-long chains (ILP), merged ascending-k with strict >
// (first-occurrence ties, matching jnp.argmax), cross-wave merge via LDS,
// wave 0 scatters with atomicAdd into the memset-zeroed output.
__global__ __launch_bounds__(256) void argmax_rel_kernel(
    const float* __restrict__ rel,   // [39,39,64]
    const float* __restrict__ x,     // [160,160,4]
    const float* __restrict__ w,     // [8,8,4,64] flat: [k][c]
    float* __restrict__ out)         // [160,160,4], pre-zeroed
{
    const int ij = blockIdx.x;                  // 0..1520
    const int i  = ij / WOUT;
    const int j  = ij - i * WOUT;
    const int wv = threadIdx.x >> 6;            // wave -> k in [wv*64, wv*64+64)
    const int c  = threadIdx.x & 63;

    // hoisted relevance load — only wave 0 consumes it after the merge
    const float r = (wv == 0) ? rel[ij * COUT + c] : 0.0f;

    const float* xp   = x + ((S * i) * WIN + (S * j)) * CIN;  // patch origin
    const int    kb   = wv * 64;                // patch rows px = 2wv, 2wv+1
    const float* rowb = xp + (2 * wv) * (WIN * CIN);

    // lane q holds x for k = kb+q: q<32 -> row0[q], q>=32 -> row1[q-32]
    const float xv    = (c < 32) ? rowb[c] : rowb[WIN * CIN + (c - 32)];
    const int   xbits = __float_as_int(xv);

    const float* wp = w + kb * COUT + c;        // coalesced over lanes

    float m0 = -__builtin_inff(), m1 = m0, m2 = m0, m3 = m0;
    int   a0 = kb, a1 = kb + 16, a2 = kb + 32, a3 = kb + 48;

    #pragma unroll
    for (int t = 0; t < 16; ++t) {
        const float x0 = __int_as_float(__builtin_amdgcn_readlane(xbits, t));
        const float x1 = __int_as_float(__builtin_amdgcn_readlane(xbits, t + 16));
        const float x2 = __int_as_float(__builtin_amdgcn_readlane(xbits, t + 32));
        const float x3 = __int_as_float(__builtin_amdgcn_readlane(xbits, t + 48));
        const float p0 = x0 * wp[(t)      * COUT];
        const float p1 = x1 * wp[(t + 16) * COUT];
        const float p2 = x2 * wp[(t + 32) * COUT];
        const float p3 = x3 * wp[(t + 48) * COUT];
        if (p0 > m0) { m0 = p0; a0 = kb + t; }
        if (p1 > m1) { m1 = p1; a1 = kb + 16 + t; }
        if (p2 > m2) { m2 = p2; a2 = kb + 32 + t; }
        if (p3 > m3) { m3 = p3; a3 = kb + 48 + t; }
    }

    // merge 4 chains, ascending k, strict > keeps earliest k on ties
    float m = m0; int a = a0;
    if (m1 > m) { m = m1; a = a1; }
    if (m2 > m) { m = m2; a = a2; }
    if (m3 > m) { m = m3; a = a3; }

    __shared__ float lm[4][COUT];
    __shared__ int   la[4][COUT];
    lm[wv][c] = m;
    la[wv][c] = a;
    __syncthreads();

    if (wv == 0) {
        float bm = lm[0][c]; int ba = la[0][c];
        #pragma unroll
        for (int s = 1; s < 4; ++s) {            // ascending k segments
            const float sm = lm[s][c];
            if (sm > bm) { bm = sm; ba = la[s][c]; }
        }
        // ba = (px*8+py)*4+pc ; flat output index
        const int px_  = ba >> 5;               // patch row
        const int rem  = ba & 31;               // py*4+pc
        const int gx   = S * i + px_;
        const int flat = gx * (WIN * CIN) + (S * j) * CIN + rem;

        atomicAdd(out + flat, r);
    }
}

extern "C" void kernel_launch(void* const* d_in, const int* in_sizes, int n_in,
                              void* d_out, int out_size, void* d_ws, size_t ws_size,
                              hipStream_t stream) {
    const float* rel = (const float*)d_in[0];   // [1,39,39,64]
    const float* x   = (const float*)d_in[1];   // [1,160,160,4]
    const float* w   = (const float*)d_in[2];   // [8,8,4,64]
    float* out = (float*)d_out;                 // [1,160,160,4]

    // Output is scatter-add target: must start at zero every call.
    hipMemsetAsync(out, 0, (size_t)out_size * sizeof(float), stream);

    argmax_rel_kernel<<<HOUT * WOUT, 256, 0, stream>>>(rel, x, w, out);
}